// Round 8
// baseline (380.682 us; speedup 1.0000x reference)
//
#include <hip/hip_runtime.h>
#include <hip/hip_bf16.h>

// Problem constants (SymNetDP): B=64, S=4096, NGB=13, NG=48, DIM=3, NCH={8,8,1}
#define BATCH 64
#define SITES 4096
#define NGB 13
#define NGRP 48
#define SDIM 3

typedef __bf16 bf16x8 __attribute__((ext_vector_type(8)));
typedef float  f32x4  __attribute__((ext_vector_type(4)));

// ---------------------------------------------------------------------------
// Workspace layout (floats):
//   Avc   : 39 f32 (pad 64)                     @ 0
//   GW0F  : [48][8*13] f32 rotated W0, 4992     @ 64        (old W0 slot)
//   GW2F  : [48][104]  f32 rotated W2, 4992     @ 5056      (ends 10048)
//   U     : bf16 region (only W1 used)          @ 64
//     W1H [384][128] @ halfword 24576 (49152) | W1L @ 73728
//     (halfwords [0,19968) alias GW0F/GW2F -> disjoint from W1 @24576+)
//   A0    : (B,S,8) channel-last f32            @ 67648  (A2 aliases)
//   A1    : (B,S,8) channel-last f32            @ 2164800
//   PART  : (64,16,3)                           @ 4261952
// K-packing for L1: k = j*8 + c  (site's 8 channels contiguous).
//
// v18: L1 = v13 MFMA kernel (measured best, 125.9us — early-DMA/late-reg/
// kt-interleave staging variants all within noise; structural floor).
// L0 and L2 are replaced by direct VALU kernels: one thread = one site,
// f32 weights wave-uniform (s_load + v_fma v,s,v), no LDS/barriers/staging.
// L0: 13 gathers from a 16KB L1-resident row; 48g x (8o x 13j) fma + softplus.
// L2: 13x32B gathers from a 128KB L2-resident slab; 48 acc x 104 fma.
// Both fully resident, static-index accumulators (no scratch).
// ---------------------------------------------------------------------------
#define OFF_AVC  0
#define OFF_GW0F 64
#define OFF_GW2F 5056
#define OFF_U    64
#define OFF_A0   67648
#define OFF_A1   2164800
#define OFF_PART 4261952
#define UW1H 24576
#define UW1L 73728

__device__ __forceinline__ float softplus_f(float h) {
    return fmaxf(h, 0.f) + __logf(1.f + __expf(-fabsf(h)));
}

// ---------------------------------------------------------------------------
// Precompute: f32 rotated tables for L0/L2 (VALU path), bf16 hi/lo split W1
// ([row=o*48+g][128], k=j*8+c), and Avc.
// ---------------------------------------------------------------------------
__global__ __launch_bounds__(256) void precompute_kernel(
    const float* __restrict__ Psi0, const float* __restrict__ Psi1,
    const float* __restrict__ Psi2, const float* __restrict__ wtVC,
    const float* __restrict__ gdiags, const int* __restrict__ perms,
    float* __restrict__ ws)
{
    float*  Avc  = ws + OFF_AVC;
    float*  GW0F = ws + OFF_GW0F;
    float*  GW2F = ws + OFF_GW2F;
    __bf16* U    = (__bf16*)(ws + OFF_U);
    int t = blockIdx.x * 256 + threadIdx.x;
    if (t < 4992) {                        // GW0F: [g][o*13+j]
        int g = t / 104, r = t % 104;
        int o = r / NGB, j = r % NGB;
        GW0F[t] = Psi0[o * NGB + perms[g * NGB + j]];
    } else if (t < 9984) {                 // GW2F: [g][k=j*8+c]
        int u = t - 4992;
        int g = u / 104, k = u % 104;
        int j = k >> 3, c = k & 7;
        GW2F[u] = Psi2[c * NGB + perms[g * NGB + j]];
    } else if (t < 9984 + 49152) {         // W1: [384][128], k=j*8+c
        int u = t - 9984;
        int k = u & 127, row = u >> 7;
        int o = row / NGRP, g = row - o * NGRP;
        float w = 0.f;
        if (k < 104) { int j = k >> 3, c = k & 7;
                       w = Psi1[(o * 8 + c) * NGB + perms[g * NGB + j]]; }
        __bf16 hi = (__bf16)w;
        U[UW1H + u] = hi;
        U[UW1L + u] = (__bf16)(w - (float)hi);
    } else if (t < 59136 + 39 * NGRP) {    // Avc
        int t2 = t - 59136;
        int g = t2 % NGRP, u = t2 / NGRP;
        int d = u / NGB, n = u % NGB;
        const int row = g * SDIM + d;
        float s = 0.f;
        for (int k = 0; k < NGRP * SDIM; k++) {
            int g2 = k / SDIM, d2 = k - g2 * SDIM;
            float p = wtVC[d2 * NGB + perms[g2 * NGB + n]];
            s = fmaf(gdiags[row * (NGRP * SDIM) + k], p, s);
        }
        atomicAdd(&Avc[u], s * (1.f / 48.f));
    }
}

// ---------------------------------------------------------------------------
// L0 (VALU): out0[b,s,o] = (1/48) sum_g softplus(b0[o] + sum_j GW0[g,o,j] *
// In[b, NN[j,s]]).  One thread per site; In row (16KB) is L1-resident;
// weights uniform -> s_load; all accumulators statically indexed.
// ---------------------------------------------------------------------------
__global__ __launch_bounds__(256) void l0_valu(
    const float* __restrict__ In,     // (B, S)
    const float* __restrict__ GW0F,   // [48][8*13]
    const float* __restrict__ bias0,  // (8,)
    const int*   __restrict__ NN,     // (13, S)
    float* __restrict__ A0)           // (B, S, 8)
{
    const int b = blockIdx.x >> 4;
    const int s = ((blockIdx.x & 15) << 8) + threadIdx.x;
    const float* row = In + (size_t)b * SITES;

    int nn[NGB];
#pragma unroll
    for (int j = 0; j < NGB; j++) nn[j] = NN[j * SITES + s];
    float x[NGB];
#pragma unroll
    for (int j = 0; j < NGB; j++) x[j] = row[nn[j]];

    float bo[8];
#pragma unroll
    for (int o = 0; o < 8; o++) bo[o] = bias0[o];

    float a[8];
#pragma unroll
    for (int o = 0; o < 8; o++) a[o] = 0.f;

#pragma unroll 2
    for (int g = 0; g < NGRP; g++) {
        const float* w = GW0F + g * 104;
        float h[8];
#pragma unroll
        for (int o = 0; o < 8; o++) h[o] = bo[o];
#pragma unroll
        for (int o = 0; o < 8; o++)
#pragma unroll
            for (int j = 0; j < NGB; j++)
                h[o] = fmaf(w[o * NGB + j], x[j], h[o]);
#pragma unroll
        for (int o = 0; o < 8; o++) a[o] += softplus_f(h[o]);
    }

    float* dst = A0 + ((size_t)(b * SITES + s)) * 8;
    f32x4 v0 = {a[0], a[1], a[2], a[3]};
    f32x4 v1 = {a[4], a[5], a[6], a[7]};
    const float k = 1.f / 48.f;
    v0 *= k; v1 *= k;
    *(f32x4*)(dst)     = v0;
    *(f32x4*)(dst + 4) = v1;
}

// ---------------------------------------------------------------------------
// L2 (VALU): out2[b,s] = (1/48) sum_g softplus(b2 + sum_{j,c} GW2[g,j*8+c] *
// A1[b, NN[j,s], c]).  One thread per site; 13 x 32B gathers (A1 slab 128KB,
// L2-resident); 48 static accumulators; weights uniform -> s_load.
// ---------------------------------------------------------------------------
__global__ __launch_bounds__(256) void l2_valu(
    const float* __restrict__ A1,     // (B, S, 8)
    const float* __restrict__ GW2F,   // [48][104]
    const float* __restrict__ bias2,  // (1,)
    const int*   __restrict__ NN,     // (13, S)
    float* __restrict__ A2)           // (B, S)
{
    const int b = blockIdx.x >> 4;
    const int s = ((blockIdx.x & 15) << 8) + threadIdx.x;

    int nn[NGB];
#pragma unroll
    for (int j = 0; j < NGB; j++) nn[j] = NN[j * SITES + s];

    const float b2 = bias2[0];
    float acc[NGRP];
#pragma unroll
    for (int g = 0; g < NGRP; g++) acc[g] = b2;

#pragma unroll 2
    for (int j = 0; j < NGB; j++) {
        const float4* p = (const float4*)(A1 + ((size_t)(b * SITES + nn[j])) * 8);
        float4 u0 = p[0], u1 = p[1];
        float x[8] = {u0.x, u0.y, u0.z, u0.w, u1.x, u1.y, u1.z, u1.w};
        const float* w = GW2F + j * 8;
#pragma unroll
        for (int g = 0; g < NGRP; g++)
#pragma unroll
            for (int c = 0; c < 8; c++)
                acc[g] = fmaf(w[g * 104 + c], x[c], acc[g]);
    }

    float a = 0.f;
#pragma unroll
    for (int g = 0; g < NGRP; g++) a += softplus_f(acc[g]);
    A2[(size_t)b * SITES + s] = a * (1.f / 48.f);
}

// ---------------------------------------------------------------------------
// MFMA gconv layer L1 (bf16x3 split), v13 structure (measured best).
// Persistent-lite: per iteration compute chunk c from buffer c&1, epilogue,
// THEN gather+convert+ds_write chunk c+1 (indices prefetched; only nnA ints
// cross the compute phase -> no spill). Product-major MFMA order.
// ---------------------------------------------------------------------------
template<int NCIN, int NCTOT, int CT, int KPAD, int KSTR, int NWAVES, int NWN,
         int CHUNKS>
__global__ __launch_bounds__(NWAVES * 64) void layer_mfma(
    const float* __restrict__ prev,   // (B,S,8)
    const __bf16* __restrict__ Wh,    // [NCTOT*48][KPAD]
    const __bf16* __restrict__ Wl,
    const float* __restrict__ bias,   // (NCTOT,)
    const int*   __restrict__ NN,     // (13, S)
    float* __restrict__ out)          // (B,S,NCTOT) channel-last
{
    constexpr int NTHR   = NWAVES * 64;
    constexpr int M      = NCTOT * NGRP;
    constexpr int MTILES = M / 16, NTILES = CT / 16;
    constexpr int NWM    = NWAVES / NWN;
    constexpr int MT_W   = MTILES / NWM, NT_W = NTILES / NWN;
    constexpr int KT     = KPAD / 32;
    constexpr int GS     = NGB * CT;              // gathered sites per chunk
    constexpr int SPT    = (GS + NTHR - 1) / NTHR;
    constexpr int CPB    = SITES / CT;            // chunks per batch
    constexpr int BUF    = CT * KSTR;             // halfwords per LDS buffer
    constexpr int BPB    = CPB / CHUNKS;          // blocks per batch

    static_assert(MT_W * 16 == NGRP, "wave covers exactly one o");
    static_assert(NWM * MT_W == MTILES && NWN * NT_W == NTILES, "");
    static_assert((KPAD & 31) == 0 && (KSTR & 7) == 0, "");
    static_assert(CPB % CHUNKS == 0, "block stays within one batch");
    static_assert(NCIN == 8, "v18: only the 8-channel layer uses MFMA");

    __shared__ __bf16 xh_lds[2 * BUF];
    __shared__ __bf16 xl_lds[2 * BUF];

    const int tid  = threadIdx.x;
    const int wave = tid >> 6, lane = tid & 63;
    const int m16  = lane & 15, quad = lane >> 4;

    const int bid    = blockIdx.x;
    const int b      = bid / BPB;
    const int octet  = bid % BPB;
    const int s0base = octet * (CHUNKS * CT);

    // --- per-thread staged-site slots (static decomposition) ----------------
    int sj[SPT], scol[SPT];
    bool sv[SPT];
#pragma unroll
    for (int i = 0; i < SPT; i++) {
        int site = tid + i * NTHR;
        sv[i] = (site < GS);
        int ss = sv[i] ? site : 0;
        sj[i] = ss / CT;
        scol[i] = ss % CT;
    }

    // staging of one site: load -> hi/lo split -> LDS write (consumed at once)
    auto stage_site = [&](int i, int nn, __bf16* dh, __bf16* dl) {
        const float4* p4 = (const float4*)(prev + ((size_t)(b * SITES + nn)) * 8);
        float4 u0 = p4[0], u1 = p4[1];
        float v[8] = {u0.x, u0.y, u0.z, u0.w, u1.x, u1.y, u1.z, u1.w};
        bf16x8 hv, lv;
#pragma unroll
        for (int c8 = 0; c8 < 8; c8++) {
            __bf16 hi = (__bf16)v[c8];
            hv[c8] = hi;
            lv[c8] = (__bf16)(v[c8] - (float)hi);
        }
        *(bf16x8*)(dh + scol[i] * KSTR + sj[i] * 8) = hv;
        *(bf16x8*)(dl + scol[i] * KSTR + sj[i] * 8) = lv;
    };

    // --- zero the K-pad region of BOTH buffers once -------------------------
    {
        const bf16x8 z8 = {};
        for (int e = tid; e < 2 * CT * 3; e += NTHR) {
            int buf = e / (CT * 3);
            int r   = e % (CT * 3);
            int col = r % CT, z = r / CT;
            *(bf16x8*)(xh_lds + buf * BUF + col * KSTR + 104 + z * 8) = z8;
            *(bf16x8*)(xl_lds + buf * BUF + col * KSTR + 104 + z * 8) = z8;
        }
    }

    // --- prologue: stage chunk 0 into buffer 0; prefetch NN for chunk 1 -----
    int nnA[SPT];
#pragma unroll
    for (int i = 0; i < SPT; i++) if (sv[i]) {
        int nn = NN[sj[i] * SITES + s0base + scol[i]];
        stage_site(i, nn, xh_lds, xl_lds);
    }
    if (CHUNKS > 1) {
        const int s1 = s0base + CT;
#pragma unroll
        for (int i = 0; i < SPT; i++)
            nnA[i] = sv[i] ? NN[sj[i] * SITES + s1 + scol[i]] : 0;
    }
    __syncthreads();

    const int wave_mt0 = (wave / NWN) * MT_W;
    const int wave_nt0 = (wave % NWN) * NT_W;
    const int o_g      = (wave_mt0 * 16) / NGRP;
    const float bo     = bias[o_g];

#pragma unroll 1
    for (int c = 0; c < CHUNKS; c++) {
        const int cur = c & 1;
        const __bf16* xh = xh_lds + cur * BUF;
        const __bf16* xl = xl_lds + cur * BUF;

        // --- (1) compute chunk c from buffer cur ----------------------------
        f32x4 acc[MT_W][NT_W];
#pragma unroll
        for (int mt = 0; mt < MT_W; mt++)
#pragma unroll
            for (int nt = 0; nt < NT_W; nt++) acc[mt][nt] = (f32x4){0.f, 0.f, 0.f, 0.f};

#pragma unroll
        for (int kt = 0; kt < KT; kt++) {
            const int koff = kt * 32 + quad * 8;
            bf16x8 ah[MT_W], al[MT_W], bh[NT_W], bl[NT_W];
#pragma unroll
            for (int mt = 0; mt < MT_W; mt++) {
                int row = (wave_mt0 + mt) * 16 + m16;
                ah[mt] = *(const bf16x8*)(Wh + (size_t)row * KPAD + koff);
                al[mt] = *(const bf16x8*)(Wl + (size_t)row * KPAD + koff);
            }
#pragma unroll
            for (int nt = 0; nt < NT_W; nt++) {
                int cbase = ((wave_nt0 + nt) * 16 + m16) * KSTR + koff;
                bh[nt] = *(const bf16x8*)(xh + cbase);
                bl[nt] = *(const bf16x8*)(xl + cbase);
            }
            // product-major: 12 independent MFMAs between same-acc reuse
#pragma unroll
            for (int mt = 0; mt < MT_W; mt++)
#pragma unroll
                for (int nt = 0; nt < NT_W; nt++)
                    acc[mt][nt] = __builtin_amdgcn_mfma_f32_16x16x32_bf16(
                        ah[mt], bh[nt], acc[mt][nt], 0, 0, 0);
#pragma unroll
            for (int mt = 0; mt < MT_W; mt++)
#pragma unroll
                for (int nt = 0; nt < NT_W; nt++)
                    acc[mt][nt] = __builtin_amdgcn_mfma_f32_16x16x32_bf16(
                        al[mt], bh[nt], acc[mt][nt], 0, 0, 0);
#pragma unroll
            for (int mt = 0; mt < MT_W; mt++)
#pragma unroll
                for (int nt = 0; nt < NT_W; nt++)
                    acc[mt][nt] = __builtin_amdgcn_mfma_f32_16x16x32_bf16(
                        ah[mt], bl[nt], acc[mt][nt], 0, 0, 0);
        }

        // --- (2) epilogue: softplus + group mean (one o per wave) -----------
        const int s0c = s0base + c * CT;
#pragma unroll
        for (int nt = 0; nt < NT_W; nt++) {
            float s = 0.f;
#pragma unroll
            for (int mt = 0; mt < MT_W; mt++)
#pragma unroll
                for (int r = 0; r < 4; r++)
                    s += softplus_f(acc[mt][nt][r] + bo);
            s += __shfl_xor(s, 16);
            s += __shfl_xor(s, 32);
            if (quad == 0)
                out[((size_t)(b * SITES + s0c + (wave_nt0 + nt) * 16 + m16)) * NCTOT + o_g]
                    = s * (1.f / 48.f);
        }

        // --- (3) stage chunk c+1 into buffer cur^1 (late, v13 ordering) -----
        if (c + 1 < CHUNKS) {
            __bf16* dh = xh_lds + (cur ^ 1) * BUF;
            __bf16* dl = xl_lds + (cur ^ 1) * BUF;
#pragma unroll
            for (int i = 0; i < SPT; i++) if (sv[i])
                stage_site(i, nnA[i], dh, dl);
            if (c + 2 < CHUNKS) {
                const int s2 = s0base + (c + 2) * CT;
#pragma unroll
                for (int i = 0; i < SPT; i++)
                    nnA[i] = sv[i] ? NN[sj[i] * SITES + s2 + scol[i]] : 0;
            }
        }
        __syncthreads();
    }
}

// ---------------------------------------------------------------------------
// Reduce stage A: per (b, s-chunk) block -> 3 partial sums
// ---------------------------------------------------------------------------
__global__ __launch_bounds__(256) void reduce_a(
    const float* __restrict__ A2, const int* __restrict__ NN,
    const int* __restrict__ s2sh, const float* __restrict__ sw,
    const float* __restrict__ Avc, float* __restrict__ partial)
{
    const int b = blockIdx.x >> 4;
    const int chunk = blockIdx.x & 15;
    const int tid = threadIdx.x;
    const int s = (chunk << 8) + tid;
    const float* a = A2 + (size_t)b * SITES;

    float y0 = 0.f, y1 = 0.f, y2 = 0.f;
#pragma unroll
    for (int n = 0; n < NGB; n++) {
        float v = a[NN[n * SITES + s]];
        y0 = fmaf(Avc[n],           v, y0);
        y1 = fmaf(Avc[NGB + n],     v, y1);
        y2 = fmaf(Avc[2 * NGB + n], v, y2);
    }
    const float wgt = sw[s2sh[s]];
    y0 *= wgt; y1 *= wgt; y2 *= wgt;

    __shared__ float red[3][256];
    red[0][tid] = y0; red[1][tid] = y1; red[2][tid] = y2;
    __syncthreads();
    for (int st = 128; st > 0; st >>= 1) {
        if (tid < st) {
            red[0][tid] += red[0][tid + st];
            red[1][tid] += red[1][tid + st];
            red[2][tid] += red[2][tid + st];
        }
        __syncthreads();
    }
    if (tid < 3) partial[(b * 16 + chunk) * 3 + tid] = red[tid][0];
}

__global__ __launch_bounds__(256) void reduce_b(
    const float* __restrict__ partial, float* __restrict__ out)
{
    int t = threadIdx.x;
    if (t < BATCH * 3) {
        int b = t / 3, d = t - b * 3;
        float s = 0.f;
        for (int c = 0; c < 16; c++) s += partial[(b * 16 + c) * 3 + d];
        out[t] = s * (1.f / (float)SITES);
    }
}

// ---------------------------------------------------------------------------
extern "C" void kernel_launch(void* const* d_in, const int* in_sizes, int n_in,
                              void* d_out, int out_size, void* d_ws, size_t ws_size,
                              hipStream_t stream)
{
    const float* InStates = (const float*)d_in[0];
    const float* Psi0     = (const float*)d_in[1];
    const float* bias0    = (const float*)d_in[2];
    const float* Psi1     = (const float*)d_in[3];
    const float* bias1    = (const float*)d_in[4];
    const float* Psi2     = (const float*)d_in[5];
    const float* bias2    = (const float*)d_in[6];
    const float* wtVC     = (const float*)d_in[7];
    const float* ShellW   = (const float*)d_in[8];
    const float* gdiags   = (const float*)d_in[9];
    const int*   GnnPerms = (const int*)d_in[10];
    const int*   NNSites  = (const int*)d_in[11];
    const int*   S2Sh     = (const int*)d_in[12];

    float*  ws   = (float*)d_ws;
    float*  Avc  = ws + OFF_AVC;
    float*  GW0F = ws + OFF_GW0F;
    float*  GW2F = ws + OFF_GW2F;
    __bf16* U    = (__bf16*)(ws + OFF_U);
    float*  A0   = ws + OFF_A0;      // (B,S,8) channel-last
    float*  A1   = ws + OFF_A1;      // (B,S,8) channel-last
    float*  A2   = ws + OFF_A0;      // (B,S) alias: A0 dead once L2 runs
    float*  PART = ws + OFF_PART;

    float* out = (float*)d_out;      // (64,3) f32

    hipMemsetAsync(Avc, 0, 64 * sizeof(float), stream);
    precompute_kernel<<<239, 256, 0, stream>>>(Psi0, Psi1, Psi2, wtVC, gdiags,
                                               GnnPerms, ws);

    constexpr int CHUNKS = 8;
    constexpr int NBLK   = BATCH * (SITES / 64) / CHUNKS;   // 512 blocks

    // L0: VALU path, one thread per site
    l0_valu<<<BATCH * 16, 256, 0, stream>>>(InStates, GW0F, bias0, NNSites, A0);
    // L1: MFMA, K=104 pad 128, KSTR=136 (v13 structure)
    layer_mfma<8, 8, 64, 128, 136, 8, 1, CHUNKS><<<NBLK, 512, 0, stream>>>(
        A0, U + UW1H, U + UW1L, bias1, NNSites, A1);
    // L2: VALU path, one thread per site
    l2_valu<<<BATCH * 16, 256, 0, stream>>>(A1, GW2F, bias2, NNSites, A2);

    reduce_a<<<BATCH * 16, 256, 0, stream>>>(A2, NNSites, S2Sh, ShellW, Avc, PART);
    reduce_b<<<1, 256, 0, stream>>>(PART, out);
}

// Round 9
// 310.579 us; speedup vs baseline: 1.2257x; 1.2257x over previous
//
#include <hip/hip_runtime.h>
#include <hip/hip_bf16.h>

// Problem constants (SymNetDP): B=64, S=4096, NGB=13, NG=48, DIM=3, NCH={8,8,1}
#define BATCH 64
#define SITES 4096
#define NGB 13
#define NGRP 48
#define SDIM 3

#define LOG2E 1.44269504f
#define SPSCALE 0.014440236f   // ln2/48: converts log2-domain softplus sum

typedef __bf16 bf16x8 __attribute__((ext_vector_type(8)));
typedef float  f32x4  __attribute__((ext_vector_type(4)));

// ---------------------------------------------------------------------------
// Workspace layout (v13 storage: f32 activations):
//   Avc  : 39 f32 (pad 64)                      @ float 0
//   U    : bf16 region, 135168 elems            @ float 64
//     W0H [384][32] 12288 | W0L @12288 | W1H [384][128] @24576 (49152) |
//     W1L @73728 | W2H [48][128] @122880 (6144) | W2L @129024
//   A0   : (B,S,8) channel-last f32             @ float 67648
//   SW   : [3][4096] f32, ALIASES A0 (A0 dead once L1 done; memset+built
//          stream-ordered after L1)
//   A1   : (B,S,8) channel-last f32             @ float 2164800
//   PART : (512,3) f32 partials                 @ float 4261952
// K-packing for NCIN=8 layers: k = j*8 + c  (site's 8 channels contiguous).
//
// v19 = v13 (champion) + log2-domain softplus + SW-fused tail.
// - Weights/bias pre-scaled by log2e -> epilogue softplus drops the two
//   per-eval v_mul(log2e/ln2); ln2 folds into output consts. Softplus is
//   co-dominant with MFMA in the chunk time (48 evals x 2 trans ops /
//   thread / chunk) across all three layers.
// - reduce_a re-associated: out[b,d] = sum_s' A2[s']*SW[d,s'] with
//   SW[d,t] = sum_{n,s: NN[n,s]=t} Avc[d,n]*wgt[s]*(ln2/48)/S precomputed by
//   a 53k-edge scatter. L2's epilogue accumulates y[3] (3 fma) instead of
//   storing A2; per-block partials + tiny deterministic final_sum replace
//   reduce_a/reduce_b.
// v18 post-mortem: VALU L0/L2 issue ~5000 uniform weight loads/wave (no
// fragment reuse) -> ~50us slower than MFMA; reverted.
// ---------------------------------------------------------------------------
#define OFF_AVC  0
#define OFF_U    64
#define OFF_A0   67648
#define OFF_SW   67648
#define OFF_A1   2164800
#define OFF_PART 4261952
#define UW0H 0
#define UW0L 12288
#define UW1H 24576
#define UW1L 73728
#define UW2H 122880
#define UW2L 129024

// ---------------------------------------------------------------------------
// Precompute: rotated weights scaled by log2e, bf16 hi/lo split,
// [row=o*48+g][KPAD] with k=j*8+c packing for K=104 layers (k=j for L0);
// plus Avc (true units - vector channel is linear, no softplus).
// ---------------------------------------------------------------------------
__global__ __launch_bounds__(256) void precompute_kernel(
    const float* __restrict__ Psi0, const float* __restrict__ Psi1,
    const float* __restrict__ Psi2, const float* __restrict__ wtVC,
    const float* __restrict__ gdiags, const int* __restrict__ perms,
    float* __restrict__ ws)
{
    float*  Avc = ws + OFF_AVC;
    __bf16* U   = (__bf16*)(ws + OFF_U);
    int t = blockIdx.x * 256 + threadIdx.x;
    if (t < 12288) {                       // W0: [384][32], k=j
        int k = t & 31, row = t >> 5;
        int o = row / NGRP, g = row - o * NGRP;
        float w = (k < NGB) ? Psi0[o * NGB + perms[g * NGB + k]] * LOG2E : 0.f;
        __bf16 hi = (__bf16)w;
        U[UW0H + t] = hi;
        U[UW0L + t] = (__bf16)(w - (float)hi);
    } else if (t < 61440) {                // W1: [384][128], k=j*8+c
        int u = t - 12288;
        int k = u & 127, row = u >> 7;
        int o = row / NGRP, g = row - o * NGRP;
        float w = 0.f;
        if (k < 104) { int j = k >> 3, c = k & 7;
                       w = Psi1[(o * 8 + c) * NGB + perms[g * NGB + j]] * LOG2E; }
        __bf16 hi = (__bf16)w;
        U[UW1H + u] = hi;
        U[UW1L + u] = (__bf16)(w - (float)hi);
    } else if (t < 67584) {                // W2: [48][128], k=j*8+c
        int u = t - 61440;
        int k = u & 127, g = u >> 7;
        float w = 0.f;
        if (k < 104) { int j = k >> 3, c = k & 7;
                       w = Psi2[c * NGB + perms[g * NGB + j]] * LOG2E; }
        __bf16 hi = (__bf16)w;
        U[UW2H + u] = hi;
        U[UW2L + u] = (__bf16)(w - (float)hi);
    } else if (t < 67584 + 39 * NGRP) {    // Avc (true units)
        int t2 = t - 67584;
        int g = t2 % NGRP, u = t2 / NGRP;
        int d = u / NGB, n = u % NGB;
        const int row = g * SDIM + d;
        float s = 0.f;
        for (int k = 0; k < NGRP * SDIM; k++) {
            int g2 = k / SDIM, d2 = k - g2 * SDIM;
            float p = wtVC[d2 * NGB + perms[g2 * NGB + n]];
            s = fmaf(gdiags[row * (NGRP * SDIM) + k], p, s);
        }
        atomicAdd(&Avc[u], s * (1.f / 48.f));
    }
}

// ---------------------------------------------------------------------------
// build_sw: SW[d][t] = sum over edges (n,s) with NN[n,s]=t of
//   Avc[d,n] * ShellW[S2Sh[s]] * (ln2/48) / SITES.
// 53248 edges x 3 dims scatter; runs after L1 (SW aliases dead A0).
// ---------------------------------------------------------------------------
__global__ __launch_bounds__(256) void build_sw(
    const float* __restrict__ Avc, const int* __restrict__ NN,
    const int* __restrict__ s2sh, const float* __restrict__ shellw,
    float* __restrict__ SW)
{
    int e = blockIdx.x * 256 + threadIdx.x;    // e = n*SITES + s
    if (e < NGB * SITES) {
        int n = e / SITES, s = e - n * SITES;
        float wgt = shellw[s2sh[s]] * (SPSCALE / (float)SITES);
        int t = NN[e];
        atomicAdd(&SW[t],             Avc[n] * wgt);
        atomicAdd(&SW[SITES + t],     Avc[NGB + n] * wgt);
        atomicAdd(&SW[2 * SITES + t], Avc[2 * NGB + n] * wgt);
    }
}

// ---------------------------------------------------------------------------
// MFMA gconv layer (bf16x3 split), v13 structure (measured best).
// Persistent-lite: per iteration compute chunk c from buffer c&1, epilogue,
// THEN gather+convert+ds_write chunk c+1 (indices prefetched; only nnA ints
// cross the compute phase -> no spill). Product-major MFMA order.
// Epilogue: log2-domain softplus (weights pre-scaled by log2e):
//   softplus(h) = ln2 * [max(h',0) + log2(1 + 2^-|h'|)], ln2 in out const.
// FUSED (L2): y[3] += SW[d][site]*sraw; per-block partial at kernel end.
// ---------------------------------------------------------------------------
template<int NCIN, int NCTOT, int CT, int KPAD, int KSTR, int NWAVES, int NWN,
         int CHUNKS, int FUSED>
__global__ __launch_bounds__(NWAVES * 64) void layer_mfma(
    const float* __restrict__ prev,   // (B,S) if NCIN==1 else (B,S,8)
    const __bf16* __restrict__ Wh,    // [NCTOT*48][KPAD]
    const __bf16* __restrict__ Wl,
    const float* __restrict__ bias,   // (NCTOT,)
    const int*   __restrict__ NN,     // (13, S)
    const float* __restrict__ SWp,    // [3][SITES] (FUSED only)
    float* __restrict__ partial,      // (grid,3)   (FUSED only)
    float* __restrict__ out)          // (B,S,NCTOT) channel-last (!FUSED)
{
    constexpr int NTHR   = NWAVES * 64;
    constexpr int M      = NCTOT * NGRP;
    constexpr int MTILES = M / 16, NTILES = CT / 16;
    constexpr int NWM    = NWAVES / NWN;
    constexpr int MT_W   = MTILES / NWM, NT_W = NTILES / NWN;
    constexpr int KT     = KPAD / 32;
    constexpr int GS     = NGB * CT;              // gathered sites per chunk
    constexpr int SPT    = (GS + NTHR - 1) / NTHR;
    constexpr int CPB    = SITES / CT;            // chunks per batch
    constexpr int BUF    = CT * KSTR;             // halfwords per LDS buffer
    constexpr int BPB    = CPB / CHUNKS;          // blocks per batch

    static_assert(MT_W * 16 == NGRP, "wave covers exactly one o");
    static_assert(NWM * MT_W == MTILES && NWN * NT_W == NTILES, "");
    static_assert((KPAD & 31) == 0 && (KSTR & 7) == 0, "");
    static_assert(CPB % CHUNKS == 0, "block stays within one batch");

    __shared__ __bf16 xh_lds[2 * BUF];
    __shared__ __bf16 xl_lds[2 * BUF];

    const int tid  = threadIdx.x;
    const int wave = tid >> 6, lane = tid & 63;
    const int m16  = lane & 15, quad = lane >> 4;

    const int bid    = blockIdx.x;
    const int b      = bid / BPB;
    const int octet  = bid % BPB;
    const int s0base = octet * (CHUNKS * CT);

    // --- per-thread staged-site slots (static decomposition) ----------------
    int sj[SPT], scol[SPT];
    bool sv[SPT];
#pragma unroll
    for (int i = 0; i < SPT; i++) {
        int site = tid + i * NTHR;
        sv[i] = (site < GS);
        int ss = sv[i] ? site : 0;
        sj[i] = ss / CT;
        scol[i] = ss % CT;
    }

    // staging of one site: load -> hi/lo split -> LDS write (consumed at once)
    auto stage_site = [&](int i, int nn, __bf16* dh, __bf16* dl) {
        if constexpr (NCIN == 1) {
            float v = prev[(size_t)b * SITES + nn];
            __bf16 hi = (__bf16)v;
            dh[scol[i] * KSTR + sj[i]] = hi;
            dl[scol[i] * KSTR + sj[i]] = (__bf16)(v - (float)hi);
        } else {
            const float4* p4 = (const float4*)(prev + ((size_t)(b * SITES + nn)) * 8);
            float4 u0 = p4[0], u1 = p4[1];
            float v[8] = {u0.x, u0.y, u0.z, u0.w, u1.x, u1.y, u1.z, u1.w};
            bf16x8 hv, lv;
#pragma unroll
            for (int c8 = 0; c8 < 8; c8++) {
                __bf16 hi = (__bf16)v[c8];
                hv[c8] = hi;
                lv[c8] = (__bf16)(v[c8] - (float)hi);
            }
            *(bf16x8*)(dh + scol[i] * KSTR + sj[i] * 8) = hv;
            *(bf16x8*)(dl + scol[i] * KSTR + sj[i] * 8) = lv;
        }
    };

    // --- zero the K-pad region of BOTH buffers once -------------------------
    if constexpr (NCIN == 1) {
        for (int e = tid; e < 2 * CT * (KPAD - NGB); e += NTHR) {
            int buf = e / (CT * (KPAD - NGB));
            int r   = e % (CT * (KPAD - NGB));
            int col = r / (KPAD - NGB), p = r % (KPAD - NGB);
            xh_lds[buf * BUF + col * KSTR + NGB + p] = (__bf16)0.f;
            xl_lds[buf * BUF + col * KSTR + NGB + p] = (__bf16)0.f;
        }
    } else {
        const bf16x8 z8 = {};
        for (int e = tid; e < 2 * CT * 3; e += NTHR) {
            int buf = e / (CT * 3);
            int r   = e % (CT * 3);
            int col = r % CT, z = r / CT;
            *(bf16x8*)(xh_lds + buf * BUF + col * KSTR + 104 + z * 8) = z8;
            *(bf16x8*)(xl_lds + buf * BUF + col * KSTR + 104 + z * 8) = z8;
        }
    }

    // --- prologue: stage chunk 0 into buffer 0; prefetch NN for chunk 1 -----
    int nnA[SPT];
#pragma unroll
    for (int i = 0; i < SPT; i++) if (sv[i]) {
        int nn = NN[sj[i] * SITES + s0base + scol[i]];
        stage_site(i, nn, xh_lds, xl_lds);
    }
    if (CHUNKS > 1) {
        const int s1 = s0base + CT;
#pragma unroll
        for (int i = 0; i < SPT; i++)
            nnA[i] = sv[i] ? NN[sj[i] * SITES + s1 + scol[i]] : 0;
    }
    __syncthreads();

    const int wave_mt0 = (wave / NWN) * MT_W;
    const int wave_nt0 = (wave % NWN) * NT_W;
    const int o_g      = (wave_mt0 * 16) / NGRP;
    const float bo     = bias[o_g] * LOG2E;

    float y0 = 0.f, y1 = 0.f, y2 = 0.f;   // FUSED accumulators (DCE'd else)

#pragma unroll 1
    for (int c = 0; c < CHUNKS; c++) {
        const int cur = c & 1;
        const __bf16* xh = xh_lds + cur * BUF;
        const __bf16* xl = xl_lds + cur * BUF;

        // --- (1) compute chunk c from buffer cur ----------------------------
        f32x4 acc[MT_W][NT_W];
#pragma unroll
        for (int mt = 0; mt < MT_W; mt++)
#pragma unroll
            for (int nt = 0; nt < NT_W; nt++) acc[mt][nt] = (f32x4){0.f, 0.f, 0.f, 0.f};

#pragma unroll
        for (int kt = 0; kt < KT; kt++) {
            const int koff = kt * 32 + quad * 8;
            bf16x8 ah[MT_W], al[MT_W], bh[NT_W], bl[NT_W];
#pragma unroll
            for (int mt = 0; mt < MT_W; mt++) {
                int row = (wave_mt0 + mt) * 16 + m16;
                ah[mt] = *(const bf16x8*)(Wh + (size_t)row * KPAD + koff);
                al[mt] = *(const bf16x8*)(Wl + (size_t)row * KPAD + koff);
            }
#pragma unroll
            for (int nt = 0; nt < NT_W; nt++) {
                int cbase = ((wave_nt0 + nt) * 16 + m16) * KSTR + koff;
                bh[nt] = *(const bf16x8*)(xh + cbase);
                bl[nt] = *(const bf16x8*)(xl + cbase);
            }
            // product-major: 12 independent MFMAs between same-acc reuse
#pragma unroll
            for (int mt = 0; mt < MT_W; mt++)
#pragma unroll
                for (int nt = 0; nt < NT_W; nt++)
                    acc[mt][nt] = __builtin_amdgcn_mfma_f32_16x16x32_bf16(
                        ah[mt], bh[nt], acc[mt][nt], 0, 0, 0);
#pragma unroll
            for (int mt = 0; mt < MT_W; mt++)
#pragma unroll
                for (int nt = 0; nt < NT_W; nt++)
                    acc[mt][nt] = __builtin_amdgcn_mfma_f32_16x16x32_bf16(
                        al[mt], bh[nt], acc[mt][nt], 0, 0, 0);
#pragma unroll
            for (int mt = 0; mt < MT_W; mt++)
#pragma unroll
                for (int nt = 0; nt < NT_W; nt++)
                    acc[mt][nt] = __builtin_amdgcn_mfma_f32_16x16x32_bf16(
                        ah[mt], bl[nt], acc[mt][nt], 0, 0, 0);
        }

        // --- (2) epilogue: log2-domain softplus + group mean ----------------
        const int s0c = s0base + c * CT;
#pragma unroll
        for (int nt = 0; nt < NT_W; nt++) {
            float s = 0.f;
#pragma unroll
            for (int mt = 0; mt < MT_W; mt++)
#pragma unroll
                for (int r = 0; r < 4; r++) {
                    float h = acc[mt][nt][r] + bo;
                    s += fmaxf(h, 0.f) + __log2f(1.f + exp2f(-fabsf(h)));
                }
            s += __shfl_xor(s, 16);
            s += __shfl_xor(s, 32);
            if (quad == 0) {
                int site = s0c + (wave_nt0 + nt) * 16 + m16;
                if constexpr (FUSED) {
                    y0 = fmaf(SWp[site],             s, y0);
                    y1 = fmaf(SWp[SITES + site],     s, y1);
                    y2 = fmaf(SWp[2 * SITES + site], s, y2);
                } else {
                    out[((size_t)(b * SITES + site)) * NCTOT + o_g] = s * SPSCALE;
                }
            }
        }

        // --- (3) stage chunk c+1 into buffer cur^1 (late, v13 ordering) -----
        if (c + 1 < CHUNKS) {
            __bf16* dh = xh_lds + (cur ^ 1) * BUF;
            __bf16* dl = xl_lds + (cur ^ 1) * BUF;
#pragma unroll
            for (int i = 0; i < SPT; i++) if (sv[i])
                stage_site(i, nnA[i], dh, dl);
            if (c + 2 < CHUNKS) {
                const int s2 = s0base + (c + 2) * CT;
#pragma unroll
                for (int i = 0; i < SPT; i++)
                    nnA[i] = sv[i] ? NN[sj[i] * SITES + s2 + scol[i]] : 0;
            }
        }
        __syncthreads();
    }

    // --- FUSED: block-reduce y[3] -> per-block partial ----------------------
    if constexpr (FUSED) {
        float* red = (float*)xh_lds;   // last loop iter ended with a barrier
        red[tid] = y0;
        red[NTHR + tid] = y1;
        red[2 * NTHR + tid] = y2;
        __syncthreads();
        for (int st = NTHR / 2; st > 0; st >>= 1) {
            if (tid < st) {
                red[tid] += red[tid + st];
                red[NTHR + tid] += red[NTHR + tid + st];
                red[2 * NTHR + tid] += red[2 * NTHR + tid + st];
            }
            __syncthreads();
        }
        if (tid < 3) partial[bid * 3 + tid] = red[tid * NTHR];
    }
}

// ---------------------------------------------------------------------------
// final_sum: out[b,d] = sum over the batch's 8 octet blocks (deterministic).
// ---------------------------------------------------------------------------
__global__ __launch_bounds__(256) void final_sum(
    const float* __restrict__ partial, float* __restrict__ out)
{
    int t = threadIdx.x;
    if (t < BATCH * 3) {
        int b = t / 3, d = t - b * 3;
        float s = 0.f;
        for (int o = 0; o < 8; o++) s += partial[(b * 8 + o) * 3 + d];
        out[t] = s;
    }
}

// ---------------------------------------------------------------------------
extern "C" void kernel_launch(void* const* d_in, const int* in_sizes, int n_in,
                              void* d_out, int out_size, void* d_ws, size_t ws_size,
                              hipStream_t stream)
{
    const float* InStates = (const float*)d_in[0];
    const float* Psi0     = (const float*)d_in[1];
    const float* bias0    = (const float*)d_in[2];
    const float* Psi1     = (const float*)d_in[3];
    const float* bias1    = (const float*)d_in[4];
    const float* Psi2     = (const float*)d_in[5];
    const float* bias2    = (const float*)d_in[6];
    const float* wtVC     = (const float*)d_in[7];
    const float* ShellW   = (const float*)d_in[8];
    const float* gdiags   = (const float*)d_in[9];
    const int*   GnnPerms = (const int*)d_in[10];
    const int*   NNSites  = (const int*)d_in[11];
    const int*   S2Sh     = (const int*)d_in[12];

    float*  ws   = (float*)d_ws;
    float*  Avc  = ws + OFF_AVC;
    __bf16* U    = (__bf16*)(ws + OFF_U);
    float*  A0   = ws + OFF_A0;      // (B,S,8) channel-last
    float*  SW   = ws + OFF_SW;      // [3][4096], aliases A0 (dead after L1)
    float*  A1   = ws + OFF_A1;      // (B,S,8) channel-last
    float*  PART = ws + OFF_PART;    // (512,3)

    float* out = (float*)d_out;      // (64,3) f32

    hipMemsetAsync(Avc, 0, 64 * sizeof(float), stream);
    precompute_kernel<<<272, 256, 0, stream>>>(Psi0, Psi1, Psi2, wtVC, gdiags,
                                               GnnPerms, ws);

    constexpr int CHUNKS = 8;
    constexpr int NBLK   = BATCH * (SITES / 64) / CHUNKS;   // 512 blocks

    // L0: K=13 pad 32, KSTR=40 (80B rows, stride 20 words -> 2-way free)
    layer_mfma<1, 8, 64, 32, 40, 8, 1, CHUNKS, 0><<<NBLK, 512, 0, stream>>>(
        InStates, U + UW0H, U + UW0L, bias0, NNSites, nullptr, nullptr, A0);
    // L1: K=104 pad 128, KSTR=136 (272B rows, stride 68 words -> 2-way free)
    layer_mfma<8, 8, 64, 128, 136, 8, 1, CHUNKS, 0><<<NBLK, 512, 0, stream>>>(
        A0, U + UW1H, U + UW1L, bias1, NNSites, nullptr, nullptr, A1);

    // SW build (stream-ordered after L1: A0 region is dead)
    hipMemsetAsync(SW, 0, 3 * SITES * sizeof(float), stream);
    build_sw<<<(NGB * SITES + 255) / 256, 256, 0, stream>>>(
        Avc, NNSites, S2Sh, ShellW, SW);

    // L2: K=104 pad 128, M=48 (1 o), 4 waves split cols; fused SW tail
    layer_mfma<8, 1, 64, 128, 136, 4, 4, CHUNKS, 1><<<NBLK, 256, 0, stream>>>(
        A1, U + UW2H, U + UW2L, bias2, NNSites, SW, PART, nullptr);

    final_sum<<<1, 256, 0, stream>>>(PART, out);
}